// Round 3
// baseline (381.752 us; speedup 1.0000x reference)
//
#include <hip/hip_runtime.h>
#include <hip/hip_bf16.h>

// Problem constants
#define Bc   2
#define Nc   4096
#define Hc   4
#define HIDc 256
#define VDc  64

typedef short s8v  __attribute__((ext_vector_type(8)));
typedef float f4v  __attribute__((ext_vector_type(4)));

// ---------------------------------------------------------------------------
// K1: V[b,h,n,k] = sum_j x[b,n,j] * W[h,j,k]; store TRANSPOSED as VT[b,h,k,n] bf16
// grid = B*H*(N/64) = 512 blocks, 256 threads.
// xs padded to stride 260 (breaks stride-256 bank aliasing); j unrolled x4 with
// ds_read_b128 instead of 4 scalar ds_read_b32 per iter.
// ---------------------------------------------------------------------------
#define XSP 260

__global__ __launch_bounds__(256) void value_kernel(
    const float* __restrict__ x, const float* __restrict__ wgt,
    unsigned short* __restrict__ vt_g)
{
    __shared__ float xs[64 * XSP];           // 66.6 KB
    __shared__ unsigned short ob[64 * 64];   // 8 KB: out tile [k][n] bf16

    int t  = threadIdx.x;
    int bid = blockIdx.x;
    int nt = bid & 63;
    int h  = (bid >> 6) & 3;
    int b  = bid >> 8;
    int n0 = nt * 64;

    const float* xg = x + ((size_t)b * Nc + n0) * HIDc;
    #pragma unroll
    for (int i = 0; i < 16; i++) {
        int id = t + i * 256;
        int row = id >> 6, ch = id & 63;
        *(float4*)&xs[row * XSP + ch * 4] = ((const float4*)xg)[id];
    }
    __syncthreads();

    int k4 = t & 15;      // float4-group of k (k = k4*4 .. +3)
    int ns = t >> 4;      // n sub-row
    const float4* wg4 = (const float4*)(wgt + (size_t)h * HIDc * VDc);

    float4 acc[4];
    #pragma unroll
    for (int i = 0; i < 4; i++) acc[i] = (float4){0.f, 0.f, 0.f, 0.f};

    for (int j = 0; j < HIDc; j += 4) {
        float4 w0 = wg4[(j + 0) * 16 + k4];
        float4 w1 = wg4[(j + 1) * 16 + k4];
        float4 w2 = wg4[(j + 2) * 16 + k4];
        float4 w3 = wg4[(j + 3) * 16 + k4];
        #pragma unroll
        for (int i = 0; i < 4; i++) {
            float4 xv = *(const float4*)&xs[(ns + i * 16) * XSP + j];
            acc[i].x += xv.x * w0.x + xv.y * w1.x + xv.z * w2.x + xv.w * w3.x;
            acc[i].y += xv.x * w0.y + xv.y * w1.y + xv.z * w2.y + xv.w * w3.y;
            acc[i].z += xv.x * w0.z + xv.y * w1.z + xv.z * w2.z + xv.w * w3.z;
            acc[i].w += xv.x * w0.w + xv.y * w1.w + xv.z * w2.w + xv.w * w3.w;
        }
    }
    #pragma unroll
    for (int i = 0; i < 4; i++) {
        int nn = ns + i * 16;
        float a[4] = {acc[i].x, acc[i].y, acc[i].z, acc[i].w};
        #pragma unroll
        for (int c = 0; c < 4; c++) {
            __hip_bfloat16 hb = __float2bfloat16(a[c]);
            ob[(k4 * 4 + c) * 64 + nn] = *(unsigned short*)&hb;
        }
    }
    __syncthreads();

    unsigned short* vg = vt_g + (((size_t)b * Hc + h) * VDc) * Nc + n0;
    #pragma unroll
    for (int i = 0; i < 16; i++) {
        int idx = t + i * 256;
        int kk = idx >> 6, nn = idx & 63;
        vg[(size_t)kk * Nc + nn] = ob[idx];   // coalesced over nn
    }
}

// ---------------------------------------------------------------------------
// K2: per-row exact 30th percentile (ranks 1228/1229) + row min.
// Mask is head-independent (scaled = m_dist*r^2, monotone). 8192 blocks x 256.
// ---------------------------------------------------------------------------
__global__ __launch_bounds__(256) void thresh_kernel(
    const float* __restrict__ m_dist,
    float* __restrict__ thr_out, float* __restrict__ min_out)
{
    __shared__ unsigned int hist[1024];
    __shared__ float wred[4];
    __shared__ unsigned int wscan[4];
    __shared__ int b0s, b1s;
    __shared__ unsigned int c0s;
    __shared__ unsigned int ncand;
    __shared__ float cand[256];
    __shared__ float s0s, s1s;

    int t = threadIdx.x;
    size_t rowid = blockIdx.x;
    const float* row = m_dist + rowid * Nc;

    for (int i = t; i < 1024; i += 256) hist[i] = 0u;
    if (t == 0) ncand = 0u;
    __syncthreads();

    float4 vals[4];
    float lmin = 1e30f;
    #pragma unroll
    for (int i = 0; i < 4; i++) {
        float4 v = ((const float4*)row)[t + i * 256];
        vals[i] = v;
        lmin = fminf(lmin, fminf(fminf(v.x, v.y), fminf(v.z, v.w)));
        atomicAdd(&hist[min(1023, (int)(v.x * 1024.0f))], 1u);
        atomicAdd(&hist[min(1023, (int)(v.y * 1024.0f))], 1u);
        atomicAdd(&hist[min(1023, (int)(v.z * 1024.0f))], 1u);
        atomicAdd(&hist[min(1023, (int)(v.w * 1024.0f))], 1u);
    }
    // min reduce
    #pragma unroll
    for (int o = 32; o > 0; o >>= 1) lmin = fminf(lmin, __shfl_xor(lmin, o));
    if ((t & 63) == 0) wred[t >> 6] = lmin;
    __syncthreads();
    float rmin = fminf(fminf(wred[0], wred[1]), fminf(wred[2], wred[3]));

    // scan: thread t owns bins 4t..4t+3
    unsigned int c[4], csum = 0;
    #pragma unroll
    for (int j = 0; j < 4; j++) { c[j] = hist[t * 4 + j]; csum += c[j]; }
    unsigned int inc = csum;
    #pragma unroll
    for (int o = 1; o < 64; o <<= 1) {
        unsigned int nv = __shfl_up(inc, o);
        if ((t & 63) >= o) inc += nv;
    }
    if ((t & 63) == 63) wscan[t >> 6] = inc;
    __syncthreads();
    unsigned int wpref = 0;
    for (int wv = 0; wv < (t >> 6); wv++) wpref += wscan[wv];
    unsigned int P = wpref + inc - csum;    // values in bins < 4t

    const unsigned int R0 = 1228u, R1 = 1229u;   // 0-indexed order stats
    unsigned int cum = P;
    #pragma unroll
    for (int j = 0; j < 4; j++) {
        unsigned int lo = cum, hi = cum + c[j];
        if (R0 >= lo && R0 < hi) { b0s = t * 4 + j; c0s = lo; }
        if (R1 >= lo && R1 < hi) { b1s = t * 4 + j; }
        cum = hi;
    }
    __syncthreads();
    int b0 = b0s, b1 = b1s;
    unsigned int C0 = c0s;

    // gather candidates in bins [b0, b1]
    #pragma unroll
    for (int i = 0; i < 4; i++) {
        float a[4] = {vals[i].x, vals[i].y, vals[i].z, vals[i].w};
        #pragma unroll
        for (int j = 0; j < 4; j++) {
            int bx = min(1023, (int)(a[j] * 1024.0f));
            if (bx >= b0 && bx <= b1) {
                unsigned int p = atomicAdd(&ncand, 1u);
                if (p < 256u) cand[p] = a[j];
            }
        }
    }
    __syncthreads();
    unsigned int nc = min(ncand, 256u);
    if ((unsigned int)t < nc) {
        float v = cand[t];
        unsigned int rk = C0;
        for (unsigned int j = 0; j < nc; j++) {
            float u = cand[j];
            rk += (u < v || (u == v && j < (unsigned int)t)) ? 1u : 0u;
        }
        if (rk == R0) s0s = v;
        if (rk == R1) s1s = v;
    }
    __syncthreads();
    if (t == 0) {
        thr_out[rowid] = 0.5f * (s0s + s1s);  // any value in [s0,s1) gives same mask
        min_out[rowid] = rmin;
    }
}

// ---------------------------------------------------------------------------
// K3: fused mask + softmax-numerator + PV (bf16 MFMA), split-K over j.
// grid = S * B * (N/32) blocks, 512 threads (8 waves: wave = (rowhalf, head)).
// Register-prefetch software pipeline: write tile k to LDS, barrier, ISSUE
// tile k+1 global loads, compute tile k (loads in flight under compute).
// LDS layouts (MPAD=68 f32, WPAD=72 bf16) verified conflict-free for b128.
// ---------------------------------------------------------------------------
#define NT 32
#define JT 64
#define MPAD 68
#define WPAD 72

__global__ __launch_bounds__(512, 6) void attn_kernel(
    const float* __restrict__ m_dist, const float* __restrict__ rr,
    const unsigned short* __restrict__ vt_g,
    const float* __restrict__ thr_g, const float* __restrict__ min_g,
    float* __restrict__ Op, float* __restrict__ Zp, int jlen)
{
    __shared__ float ms[NT * MPAD];                 // 8.7 KB
    __shared__ unsigned short vt[Hc * VDc * WPAD];  // 36.9 KB

    int t = threadIdx.x;
    const int nblk = Bc * (Nc / NT);        // 256
    int js = blockIdx.x / nblk;
    int rb = blockIdx.x - js * nblk;
    int b  = rb >> 7;                       // Nc/NT = 128 row-tiles
    int n0 = (rb & 127) * NT;
    int j0 = js * jlen;

    int lane = t & 63, q = lane >> 4, m16 = lane & 15;
    int w = t >> 6;                         // wave 0..7
    int h = w & 3, rh = w >> 2;
    int row = rh * 16 + m16;                // local A-row this lane owns

    float th = thr_g[b * Nc + n0 + row];
    float mn = min_g[b * Nc + n0 + row];
    float rv = rr[h];
    float cc = -(rv * rv) * 1.4426950408889634f;   // -r^2 * log2(e)

    f4v acc[4];
    #pragma unroll
    for (int ct = 0; ct < 4; ct++) acc[ct] = (f4v){0.f, 0.f, 0.f, 0.f};
    float zacc = 0.f;

    const float* mbase = m_dist + ((size_t)b * Nc + n0) * Nc + j0;
    const unsigned short* vtb = vt_g + ((size_t)b * Hc * VDc) * Nc + j0;

    // staging thread->element maps
    int mrow = t >> 4, mch = t & 15;                 // ms: 32 rows x 16 float4
    const float* mptr = mbase + (size_t)mrow * Nc + mch * 4;
    int vrow0 = t >> 3, vch = t & 7;                 // vt: rows t>>3 + i*64

    // prologue: prefetch tile 0
    float4 pm = *(const float4*)(mptr);
    float4 pv[4];
    #pragma unroll
    for (int i = 0; i < 4; i++)
        pv[i] = *(const float4*)(vtb + (size_t)(vrow0 + i * 64) * Nc + vch * 8);

    for (int jt = 0; jt < jlen; jt += JT) {
        // write prefetched tile to LDS
        *(float4*)&ms[mrow * MPAD + mch * 4] = pm;
        #pragma unroll
        for (int i = 0; i < 4; i++)
            *(float4*)&vt[(vrow0 + i * 64) * WPAD + vch * 8] = pv[i];
        __syncthreads();

        // issue next tile's global loads (complete under compute below)
        if (jt + JT < jlen) {
            pm = *(const float4*)(mptr + jt + JT);
            #pragma unroll
            for (int i = 0; i < 4; i++)
                pv[i] = *(const float4*)(vtb + (size_t)(vrow0 + i * 64) * Nc + (jt + JT) + vch * 8);
        }

        const unsigned short* vb = &vt[(h * VDc) * WPAD];
        #pragma unroll
        for (int ks = 0; ks < 2; ks++) {
            // A-fragment in-register: w[row][j = ks*32 + q*8 + 0..7]
            float4 a0 = *(const float4*)&ms[row * MPAD + ks * 32 + q * 8];
            float4 a1 = *(const float4*)&ms[row * MPAD + ks * 32 + q * 8 + 4];
            float w0 = (a0.x <= th) ? __builtin_amdgcn_exp2f((a0.x - mn) * cc) : 0.f;
            float w1 = (a0.y <= th) ? __builtin_amdgcn_exp2f((a0.y - mn) * cc) : 0.f;
            float w2 = (a0.z <= th) ? __builtin_amdgcn_exp2f((a0.z - mn) * cc) : 0.f;
            float w3 = (a0.w <= th) ? __builtin_amdgcn_exp2f((a0.w - mn) * cc) : 0.f;
            float w4 = (a1.x <= th) ? __builtin_amdgcn_exp2f((a1.x - mn) * cc) : 0.f;
            float w5 = (a1.y <= th) ? __builtin_amdgcn_exp2f((a1.y - mn) * cc) : 0.f;
            float w6 = (a1.z <= th) ? __builtin_amdgcn_exp2f((a1.z - mn) * cc) : 0.f;
            float w7 = (a1.w <= th) ? __builtin_amdgcn_exp2f((a1.w - mn) * cc) : 0.f;
            zacc += ((w0 + w1) + (w2 + w3)) + ((w4 + w5) + (w6 + w7));
            union { unsigned short s[8]; s8v v; } afu;
            __hip_bfloat16 hb;
            hb = __float2bfloat16(w0); afu.s[0] = *(unsigned short*)&hb;
            hb = __float2bfloat16(w1); afu.s[1] = *(unsigned short*)&hb;
            hb = __float2bfloat16(w2); afu.s[2] = *(unsigned short*)&hb;
            hb = __float2bfloat16(w3); afu.s[3] = *(unsigned short*)&hb;
            hb = __float2bfloat16(w4); afu.s[4] = *(unsigned short*)&hb;
            hb = __float2bfloat16(w5); afu.s[5] = *(unsigned short*)&hb;
            hb = __float2bfloat16(w6); afu.s[6] = *(unsigned short*)&hb;
            hb = __float2bfloat16(w7); afu.s[7] = *(unsigned short*)&hb;
            #pragma unroll
            for (int ct = 0; ct < 4; ct++) {
                s8v bf = *(const s8v*)(vb + (ct * 16 + m16) * WPAD + ks * 32 + q * 8);
                acc[ct] = __builtin_amdgcn_mfma_f32_16x16x32_bf16(afu.v, bf, acc[ct], 0, 0, 0);
            }
        }
        __syncthreads();
    }

    // Z: lanes sharing m16 across q (xor 16, 32)
    zacc += __shfl_xor(zacc, 16);
    zacc += __shfl_xor(zacc, 32);
    if (q == 0)
        Zp[(((size_t)js * Bc + b) * Hc + h) * Nc + n0 + row] = zacc;

    // partial O: D row = q*4+rg (within the 16), col = ct*16+m16
    #pragma unroll
    for (int ct = 0; ct < 4; ct++) {
        #pragma unroll
        for (int rg = 0; rg < 4; rg++) {
            int nl = rh * 16 + q * 4 + rg;
            Op[(((size_t)js * Bc + b) * Nc + n0 + nl) * HIDc + h * VDc + ct * 16 + m16]
                = acc[ct][rg];
        }
    }
}

// ---------------------------------------------------------------------------
// K4: combine split-K partials, normalize, exact GELU. f32x4 per thread.
// grid = B*N*HID/1024 = 2048 blocks x 256.
// ---------------------------------------------------------------------------
__global__ __launch_bounds__(256) void combine_kernel(
    const float* __restrict__ Op, const float* __restrict__ Zp,
    float* __restrict__ out, int S)
{
    int g = blockIdx.x * 256 + threadIdx.x;       // float4 index
    int c4 = g & 63;
    int n  = (g >> 6) & (Nc - 1);
    int b  = g >> 18;                             // 64 * 4096 = 2^18
    int h  = c4 >> 4;

    float z = 0.f;
    float4 v = {0.f, 0.f, 0.f, 0.f};
    for (int s = 0; s < S; s++) {
        z += Zp[(((size_t)s * Bc + b) * Hc + h) * Nc + n];
        float4 p = *(const float4*)&Op[(((size_t)s * Bc + b) * Nc + n) * HIDc + c4 * 4];
        v.x += p.x; v.y += p.y; v.z += p.z; v.w += p.w;
    }
    float iz = 1.0f / z;
    float4 o;
    float u;
    u = v.x * iz; o.x = 0.5f * u * (1.0f + erff(u * 0.7071067811865476f));
    u = v.y * iz; o.y = 0.5f * u * (1.0f + erff(u * 0.7071067811865476f));
    u = v.z * iz; o.z = 0.5f * u * (1.0f + erff(u * 0.7071067811865476f));
    u = v.w * iz; o.w = 0.5f * u * (1.0f + erff(u * 0.7071067811865476f));
    *(float4*)&out[(((size_t)b * Nc + n) * HIDc) + c4 * 4] = o;
}

// ---------------------------------------------------------------------------
extern "C" void kernel_launch(void* const* d_in, const int* in_sizes, int n_in,
                              void* d_out, int out_size, void* d_ws, size_t ws_size,
                              hipStream_t stream) {
    const float* m_dist = (const float*)d_in[0];
    const float* x      = (const float*)d_in[1];
    const float* r      = (const float*)d_in[2];
    const float* weight = (const float*)d_in[3];
    float* out = (float*)d_out;

    char* ws = (char*)d_ws;
    const size_t MB = 1024 * 1024;
    unsigned short* vt = (unsigned short*)ws;            // 4 MiB bf16 VT
    float* thr = (float*)(ws + 4 * MB);                  // 32 KiB
    float* mn  = (float*)(ws + 4 * MB + 32 * 1024);      // 32 KiB
    float* Zp  = (float*)(ws + 4 * MB + 64 * 1024);      // up to 512 KiB
    float* Op  = (float*)(ws + 5 * MB);                  // S * 8 MiB

    // split factor: prefer 4 (needs 37 MiB ws), else 2, else 1
    int S = 4;
    if (ws_size < 5 * MB + 4 * (size_t)(Bc * Nc * HIDc * 4)) S = 2;
    if (ws_size < 5 * MB + 2 * (size_t)(Bc * Nc * HIDc * 4)) S = 1;
    int jlen = Nc / S;

    value_kernel<<<512, 256, 0, stream>>>(x, weight, vt);
    thresh_kernel<<<Bc * Nc, 256, 0, stream>>>(m_dist, thr, mn);
    attn_kernel<<<S * Bc * (Nc / NT), 512, 0, stream>>>(m_dist, r, vt, thr, mn, Op, Zp, jlen);
    combine_kernel<<<(Bc * Nc * HIDc) / 1024, 256, 0, stream>>>(Op, Zp, out, S);
}

// Round 4
// 281.755 us; speedup vs baseline: 1.3549x; 1.3549x over previous
//
#include <hip/hip_runtime.h>
#include <hip/hip_bf16.h>

// Problem constants
#define Bc   2
#define Nc   4096
#define Hc   4
#define HIDc 256
#define VDc  64

typedef short s8v  __attribute__((ext_vector_type(8)));
typedef float f4v  __attribute__((ext_vector_type(4)));

// ---------------------------------------------------------------------------
// K1: V[b,h,n,k] = sum_j x[b,n,j] * W[h,j,k]; store TRANSPOSED as VT[b,h,k,n] bf16
// grid = B*H*(N/64) = 512 blocks, 256 threads.
// ---------------------------------------------------------------------------
#define XSP 260

__global__ __launch_bounds__(256) void value_kernel(
    const float* __restrict__ x, const float* __restrict__ wgt,
    unsigned short* __restrict__ vt_g)
{
    __shared__ float xs[64 * XSP];           // 66.6 KB
    __shared__ unsigned short ob[64 * 64];   // 8 KB: out tile [k][n] bf16

    int t  = threadIdx.x;
    int bid = blockIdx.x;
    int nt = bid & 63;
    int h  = (bid >> 6) & 3;
    int b  = bid >> 8;
    int n0 = nt * 64;

    const float* xg = x + ((size_t)b * Nc + n0) * HIDc;
    #pragma unroll
    for (int i = 0; i < 16; i++) {
        int id = t + i * 256;
        int row = id >> 6, ch = id & 63;
        *(float4*)&xs[row * XSP + ch * 4] = ((const float4*)xg)[id];
    }
    __syncthreads();

    int k4 = t & 15;      // float4-group of k (k = k4*4 .. +3)
    int ns = t >> 4;      // n sub-row
    const float4* wg4 = (const float4*)(wgt + (size_t)h * HIDc * VDc);

    float4 acc[4];
    #pragma unroll
    for (int i = 0; i < 4; i++) acc[i] = (float4){0.f, 0.f, 0.f, 0.f};

    for (int j = 0; j < HIDc; j += 4) {
        float4 w0 = wg4[(j + 0) * 16 + k4];
        float4 w1 = wg4[(j + 1) * 16 + k4];
        float4 w2 = wg4[(j + 2) * 16 + k4];
        float4 w3 = wg4[(j + 3) * 16 + k4];
        #pragma unroll
        for (int i = 0; i < 4; i++) {
            float4 xv = *(const float4*)&xs[(ns + i * 16) * XSP + j];
            acc[i].x += xv.x * w0.x + xv.y * w1.x + xv.z * w2.x + xv.w * w3.x;
            acc[i].y += xv.x * w0.y + xv.y * w1.y + xv.z * w2.y + xv.w * w3.y;
            acc[i].z += xv.x * w0.z + xv.y * w1.z + xv.z * w2.z + xv.w * w3.z;
            acc[i].w += xv.x * w0.w + xv.y * w1.w + xv.z * w2.w + xv.w * w3.w;
        }
    }
    #pragma unroll
    for (int i = 0; i < 4; i++) {
        int nn = ns + i * 16;
        float a[4] = {acc[i].x, acc[i].y, acc[i].z, acc[i].w};
        #pragma unroll
        for (int c = 0; c < 4; c++) {
            __hip_bfloat16 hb = __float2bfloat16(a[c]);
            ob[(k4 * 4 + c) * 64 + nn] = *(unsigned short*)&hb;
        }
    }
    __syncthreads();

    unsigned short* vg = vt_g + (((size_t)b * Hc + h) * VDc) * Nc + n0;
    #pragma unroll
    for (int i = 0; i < 16; i++) {
        int idx = t + i * 256;
        int kk = idx >> 6, nn = idx & 63;
        vg[(size_t)kk * Nc + nn] = ob[idx];   // coalesced over nn
    }
}

// ---------------------------------------------------------------------------
// K2: per-row exact 30th percentile (ranks 1228/1229) + row min.
// Mask is head-independent (scaled = m_dist*r^2, monotone). 8192 blocks x 256.
// ---------------------------------------------------------------------------
__global__ __launch_bounds__(256) void thresh_kernel(
    const float* __restrict__ m_dist,
    float* __restrict__ thr_out, float* __restrict__ min_out)
{
    __shared__ unsigned int hist[1024];
    __shared__ float wred[4];
    __shared__ unsigned int wscan[4];
    __shared__ int b0s, b1s;
    __shared__ unsigned int c0s;
    __shared__ unsigned int ncand;
    __shared__ float cand[256];
    __shared__ float s0s, s1s;

    int t = threadIdx.x;
    size_t rowid = blockIdx.x;
    const float* row = m_dist + rowid * Nc;

    for (int i = t; i < 1024; i += 256) hist[i] = 0u;
    if (t == 0) ncand = 0u;
    __syncthreads();

    float4 vals[4];
    float lmin = 1e30f;
    #pragma unroll
    for (int i = 0; i < 4; i++) {
        float4 v = ((const float4*)row)[t + i * 256];
        vals[i] = v;
        lmin = fminf(lmin, fminf(fminf(v.x, v.y), fminf(v.z, v.w)));
        atomicAdd(&hist[min(1023, (int)(v.x * 1024.0f))], 1u);
        atomicAdd(&hist[min(1023, (int)(v.y * 1024.0f))], 1u);
        atomicAdd(&hist[min(1023, (int)(v.z * 1024.0f))], 1u);
        atomicAdd(&hist[min(1023, (int)(v.w * 1024.0f))], 1u);
    }
    // min reduce
    #pragma unroll
    for (int o = 32; o > 0; o >>= 1) lmin = fminf(lmin, __shfl_xor(lmin, o));
    if ((t & 63) == 0) wred[t >> 6] = lmin;
    __syncthreads();
    float rmin = fminf(fminf(wred[0], wred[1]), fminf(wred[2], wred[3]));

    // scan: thread t owns bins 4t..4t+3
    unsigned int c[4], csum = 0;
    #pragma unroll
    for (int j = 0; j < 4; j++) { c[j] = hist[t * 4 + j]; csum += c[j]; }
    unsigned int inc = csum;
    #pragma unroll
    for (int o = 1; o < 64; o <<= 1) {
        unsigned int nv = __shfl_up(inc, o);
        if ((t & 63) >= o) inc += nv;
    }
    if ((t & 63) == 63) wscan[t >> 6] = inc;
    __syncthreads();
    unsigned int wpref = 0;
    for (int wv = 0; wv < (t >> 6); wv++) wpref += wscan[wv];
    unsigned int P = wpref + inc - csum;    // values in bins < 4t

    const unsigned int R0 = 1228u, R1 = 1229u;   // 0-indexed order stats
    unsigned int cum = P;
    #pragma unroll
    for (int j = 0; j < 4; j++) {
        unsigned int lo = cum, hi = cum + c[j];
        if (R0 >= lo && R0 < hi) { b0s = t * 4 + j; c0s = lo; }
        if (R1 >= lo && R1 < hi) { b1s = t * 4 + j; }
        cum = hi;
    }
    __syncthreads();
    int b0 = b0s, b1 = b1s;
    unsigned int C0 = c0s;

    // gather candidates in bins [b0, b1]
    #pragma unroll
    for (int i = 0; i < 4; i++) {
        float a[4] = {vals[i].x, vals[i].y, vals[i].z, vals[i].w};
        #pragma unroll
        for (int j = 0; j < 4; j++) {
            int bx = min(1023, (int)(a[j] * 1024.0f));
            if (bx >= b0 && bx <= b1) {
                unsigned int p = atomicAdd(&ncand, 1u);
                if (p < 256u) cand[p] = a[j];
            }
        }
    }
    __syncthreads();
    unsigned int nc = min(ncand, 256u);
    if ((unsigned int)t < nc) {
        float v = cand[t];
        unsigned int rk = C0;
        for (unsigned int j = 0; j < nc; j++) {
            float u = cand[j];
            rk += (u < v || (u == v && j < (unsigned int)t)) ? 1u : 0u;
        }
        if (rk == R0) s0s = v;
        if (rk == R1) s1s = v;
    }
    __syncthreads();
    if (t == 0) {
        thr_out[rowid] = 0.5f * (s0s + s1s);  // any value in [s0,s1) gives same mask
        min_out[rowid] = rmin;
    }
}

// ---------------------------------------------------------------------------
// K3: fused mask + softmax-numerator + PV (bf16 MFMA), split-K over j.
// grid = S * B * (N/32) blocks, 512 threads (8 waves: wave = (rowhalf, head)).
// Round-2 structure (NO register prefetch — it spilled: R3 WRITE_SIZE 320MB).
// XOR-swizzled unpadded LDS tiles: ms 8192B + vt 32768B = 40960B exactly
// -> 4 blocks/CU; __launch_bounds__(512,8) caps VGPR at 64 for 32 waves/CU.
// Swizzle bank math: every b128 access <=2-way per 16-lane phase (free, m136).
// ---------------------------------------------------------------------------
#define NT 32
#define JT 64

__global__ __launch_bounds__(512, 8) void attn_kernel(
    const float* __restrict__ m_dist, const float* __restrict__ rr,
    const unsigned short* __restrict__ vt_g,
    const float* __restrict__ thr_g, const float* __restrict__ min_g,
    float* __restrict__ Op, float* __restrict__ Zp, int jlen)
{
    __shared__ float ms[NT * 64];                 // 8 KB, chunk c at c^(row&15)
    __shared__ unsigned short vt[Hc * VDc * 64];  // 32 KB, chunk c at c^(row&7)

    int t = threadIdx.x;
    const int nblk = Bc * (Nc / NT);        // 256
    int js = blockIdx.x / nblk;
    int rb = blockIdx.x - js * nblk;
    int b  = rb >> 7;                       // Nc/NT = 128 row-tiles
    int n0 = (rb & 127) * NT;
    int j0 = js * jlen;

    int lane = t & 63, q = lane >> 4, m16 = lane & 15;
    int w = t >> 6;                         // wave 0..7
    int h = w & 3, rh = w >> 2;
    int row = rh * 16 + m16;                // local A-row this lane owns

    float th = thr_g[b * Nc + n0 + row];
    float mn = min_g[b * Nc + n0 + row];
    float rv = rr[h];
    float cc = -(rv * rv) * 1.4426950408889634f;   // -r^2 * log2(e)

    f4v acc[4];
    #pragma unroll
    for (int ct = 0; ct < 4; ct++) acc[ct] = (f4v){0.f, 0.f, 0.f, 0.f};
    float zacc = 0.f;

    const float* mbase = m_dist + ((size_t)b * Nc + n0) * Nc + j0;
    const unsigned short* vtb = vt_g + ((size_t)b * Hc * VDc) * Nc + j0;

    // staging maps (swizzled LDS destinations)
    int mrow = t >> 4, mch = t & 15;        // ms: 32 rows x 16 float4-chunks
    int msw  = mrow * 64 + ((mch ^ (mrow & 15)) << 2);
    int vrow0 = t >> 3, vch = t & 7;        // vt: rows t>>3 + i*64, 8 chunks

    // A-read swizzled chunk offsets for this lane (row&15 == m16)
    int a00 = row * 64 + (((q * 2 + 0) ^ m16) << 2);       // ks=0
    int a01 = row * 64 + (((q * 2 + 1) ^ m16) << 2);
    int a10 = row * 64 + (((8 + q * 2 + 0) ^ m16) << 2);   // ks=1
    int a11 = row * 64 + (((8 + q * 2 + 1) ^ m16) << 2);

    for (int jt = 0; jt < jlen; jt += JT) {
        // stage ms (32 x 64 f32): 1 float4/thread, swizzled dest
        *(float4*)&ms[msw] = *(const float4*)(mbase + (size_t)mrow * Nc + jt + mch * 4);
        // stage vt (256 rows x 64 j bf16): 4 float4/thread, swizzled dest
        #pragma unroll
        for (int i = 0; i < 4; i++) {
            int rrow = vrow0 + i * 64;
            *(float4*)&vt[rrow * 64 + ((vch ^ (rrow & 7)) << 3)] =
                *(const float4*)(vtb + (size_t)rrow * Nc + jt + vch * 8);
        }
        __syncthreads();

        const unsigned short* vb = &vt[(h * VDc) * 64];
        #pragma unroll
        for (int ks = 0; ks < 2; ks++) {
            float4 a0 = *(const float4*)&ms[ks ? a10 : a00];
            float4 a1 = *(const float4*)&ms[ks ? a11 : a01];
            float w0 = (a0.x <= th) ? __builtin_amdgcn_exp2f((a0.x - mn) * cc) : 0.f;
            float w1 = (a0.y <= th) ? __builtin_amdgcn_exp2f((a0.y - mn) * cc) : 0.f;
            float w2 = (a0.z <= th) ? __builtin_amdgcn_exp2f((a0.z - mn) * cc) : 0.f;
            float w3 = (a0.w <= th) ? __builtin_amdgcn_exp2f((a0.w - mn) * cc) : 0.f;
            float w4 = (a1.x <= th) ? __builtin_amdgcn_exp2f((a1.x - mn) * cc) : 0.f;
            float w5 = (a1.y <= th) ? __builtin_amdgcn_exp2f((a1.y - mn) * cc) : 0.f;
            float w6 = (a1.z <= th) ? __builtin_amdgcn_exp2f((a1.z - mn) * cc) : 0.f;
            float w7 = (a1.w <= th) ? __builtin_amdgcn_exp2f((a1.w - mn) * cc) : 0.f;
            zacc += ((w0 + w1) + (w2 + w3)) + ((w4 + w5) + (w6 + w7));
            union { unsigned short s[8]; s8v v; } afu;
            __hip_bfloat16 hb;
            hb = __float2bfloat16(w0); afu.s[0] = *(unsigned short*)&hb;
            hb = __float2bfloat16(w1); afu.s[1] = *(unsigned short*)&hb;
            hb = __float2bfloat16(w2); afu.s[2] = *(unsigned short*)&hb;
            hb = __float2bfloat16(w3); afu.s[3] = *(unsigned short*)&hb;
            hb = __float2bfloat16(w4); afu.s[4] = *(unsigned short*)&hb;
            hb = __float2bfloat16(w5); afu.s[5] = *(unsigned short*)&hb;
            hb = __float2bfloat16(w6); afu.s[6] = *(unsigned short*)&hb;
            hb = __float2bfloat16(w7); afu.s[7] = *(unsigned short*)&hb;
            #pragma unroll
            for (int ct = 0; ct < 4; ct++) {
                int brow = ct * 16 + m16;
                s8v bf = *(const s8v*)(vb + brow * 64 + (((ks * 4 + q) ^ (m16 & 7)) << 3));
                acc[ct] = __builtin_amdgcn_mfma_f32_16x16x32_bf16(afu.v, bf, acc[ct], 0, 0, 0);
            }
        }
        __syncthreads();
    }

    // Z: lanes sharing m16 across q (xor 16, 32)
    zacc += __shfl_xor(zacc, 16);
    zacc += __shfl_xor(zacc, 32);
    if (q == 0)
        Zp[(((size_t)js * Bc + b) * Hc + h) * Nc + n0 + row] = zacc;

    // partial O: D row = q*4+rg (within the 16), col = ct*16+m16
    #pragma unroll
    for (int ct = 0; ct < 4; ct++) {
        #pragma unroll
        for (int rg = 0; rg < 4; rg++) {
            int nl = rh * 16 + q * 4 + rg;
            Op[(((size_t)js * Bc + b) * Nc + n0 + nl) * HIDc + h * VDc + ct * 16 + m16]
                = acc[ct][rg];
        }
    }
}

// ---------------------------------------------------------------------------
// K4: combine split-K partials, normalize, exact GELU. f32x4 per thread.
// grid = B*N*HID/1024 = 2048 blocks x 256.
// ---------------------------------------------------------------------------
__global__ __launch_bounds__(256) void combine_kernel(
    const float* __restrict__ Op, const float* __restrict__ Zp,
    float* __restrict__ out, int S)
{
    int g = blockIdx.x * 256 + threadIdx.x;       // float4 index
    int c4 = g & 63;
    int n  = (g >> 6) & (Nc - 1);
    int b  = g >> 18;                             // 64 * 4096 = 2^18
    int h  = c4 >> 4;

    float z = 0.f;
    float4 v = {0.f, 0.f, 0.f, 0.f};
    for (int s = 0; s < S; s++) {
        z += Zp[(((size_t)s * Bc + b) * Hc + h) * Nc + n];
        float4 p = *(const float4*)&Op[(((size_t)s * Bc + b) * Nc + n) * HIDc + c4 * 4];
        v.x += p.x; v.y += p.y; v.z += p.z; v.w += p.w;
    }
    float iz = 1.0f / z;
    float4 o;
    float u;
    u = v.x * iz; o.x = 0.5f * u * (1.0f + erff(u * 0.7071067811865476f));
    u = v.y * iz; o.y = 0.5f * u * (1.0f + erff(u * 0.7071067811865476f));
    u = v.z * iz; o.z = 0.5f * u * (1.0f + erff(u * 0.7071067811865476f));
    u = v.w * iz; o.w = 0.5f * u * (1.0f + erff(u * 0.7071067811865476f));
    *(float4*)&out[(((size_t)b * Nc + n) * HIDc) + c4 * 4] = o;
}

// ---------------------------------------------------------------------------
extern "C" void kernel_launch(void* const* d_in, const int* in_sizes, int n_in,
                              void* d_out, int out_size, void* d_ws, size_t ws_size,
                              hipStream_t stream) {
    const float* m_dist = (const float*)d_in[0];
    const float* x      = (const float*)d_in[1];
    const float* r      = (const float*)d_in[2];
    const float* weight = (const float*)d_in[3];
    float* out = (float*)d_out;

    char* ws = (char*)d_ws;
    const size_t MB = 1024 * 1024;
    unsigned short* vt = (unsigned short*)ws;            // 4 MiB bf16 VT
    float* thr = (float*)(ws + 4 * MB);                  // 32 KiB
    float* mn  = (float*)(ws + 4 * MB + 32 * 1024);      // 32 KiB
    float* Zp  = (float*)(ws + 4 * MB + 64 * 1024);      // up to 512 KiB
    float* Op  = (float*)(ws + 5 * MB);                  // S * 8 MiB

    // split factor: prefer 4 (needs 37 MiB ws), else 2, else 1
    int S = 4;
    if (ws_size < 5 * MB + 4 * (size_t)(Bc * Nc * HIDc * 4)) S = 2;
    if (ws_size < 5 * MB + 2 * (size_t)(Bc * Nc * HIDc * 4)) S = 1;
    int jlen = Nc / S;

    value_kernel<<<512, 256, 0, stream>>>(x, weight, vt);
    thresh_kernel<<<Bc * Nc, 256, 0, stream>>>(m_dist, thr, mn);
    attn_kernel<<<S * Bc * (Nc / NT), 512, 0, stream>>>(m_dist, r, vt, thr, mn, Op, Zp, jlen);
    combine_kernel<<<(Bc * Nc * HIDc) / 1024, 256, 0, stream>>>(Op, Zp, out, S);
}

// Round 5
// 277.440 us; speedup vs baseline: 1.3760x; 1.0156x over previous
//
#include <hip/hip_runtime.h>
#include <hip/hip_bf16.h>

// Problem constants
#define Bc   2
#define Nc   4096
#define Hc   4
#define HIDc 256
#define VDc  64

typedef short s8v  __attribute__((ext_vector_type(8)));
typedef float f4v  __attribute__((ext_vector_type(4)));

// ---------------------------------------------------------------------------
// K1: V[b,h,n,k] = sum_j x[b,n,j] * W[h,j,k]; store TRANSPOSED as VT[b,h,k,n] bf16
// grid = B*H*(N/64) = 512 blocks, 256 threads.
// ---------------------------------------------------------------------------
#define XSP 260

__global__ __launch_bounds__(256) void value_kernel(
    const float* __restrict__ x, const float* __restrict__ wgt,
    unsigned short* __restrict__ vt_g)
{
    __shared__ float xs[64 * XSP];           // 66.6 KB
    __shared__ unsigned short ob[64 * 64];   // 8 KB: out tile [k][n] bf16

    int t  = threadIdx.x;
    int bid = blockIdx.x;
    int nt = bid & 63;
    int h  = (bid >> 6) & 3;
    int b  = bid >> 8;
    int n0 = nt * 64;

    const float* xg = x + ((size_t)b * Nc + n0) * HIDc;
    #pragma unroll
    for (int i = 0; i < 16; i++) {
        int id = t + i * 256;
        int row = id >> 6, ch = id & 63;
        *(float4*)&xs[row * XSP + ch * 4] = ((const float4*)xg)[id];
    }
    __syncthreads();

    int k4 = t & 15;      // float4-group of k (k = k4*4 .. +3)
    int ns = t >> 4;      // n sub-row
    const float4* wg4 = (const float4*)(wgt + (size_t)h * HIDc * VDc);

    float4 acc[4];
    #pragma unroll
    for (int i = 0; i < 4; i++) acc[i] = (float4){0.f, 0.f, 0.f, 0.f};

    for (int j = 0; j < HIDc; j += 4) {
        float4 w0 = wg4[(j + 0) * 16 + k4];
        float4 w1 = wg4[(j + 1) * 16 + k4];
        float4 w2 = wg4[(j + 2) * 16 + k4];
        float4 w3 = wg4[(j + 3) * 16 + k4];
        #pragma unroll
        for (int i = 0; i < 4; i++) {
            float4 xv = *(const float4*)&xs[(ns + i * 16) * XSP + j];
            acc[i].x += xv.x * w0.x + xv.y * w1.x + xv.z * w2.x + xv.w * w3.x;
            acc[i].y += xv.x * w0.y + xv.y * w1.y + xv.z * w2.y + xv.w * w3.y;
            acc[i].z += xv.x * w0.z + xv.y * w1.z + xv.z * w2.z + xv.w * w3.z;
            acc[i].w += xv.x * w0.w + xv.y * w1.w + xv.z * w2.w + xv.w * w3.w;
        }
    }
    #pragma unroll
    for (int i = 0; i < 4; i++) {
        int nn = ns + i * 16;
        float a[4] = {acc[i].x, acc[i].y, acc[i].z, acc[i].w};
        #pragma unroll
        for (int c = 0; c < 4; c++) {
            __hip_bfloat16 hb = __float2bfloat16(a[c]);
            ob[(k4 * 4 + c) * 64 + nn] = *(unsigned short*)&hb;
        }
    }
    __syncthreads();

    unsigned short* vg = vt_g + (((size_t)b * Hc + h) * VDc) * Nc + n0;
    #pragma unroll
    for (int i = 0; i < 16; i++) {
        int idx = t + i * 256;
        int kk = idx >> 6, nn = idx & 63;
        vg[(size_t)kk * Nc + nn] = ob[idx];   // coalesced over nn
    }
}

// ---------------------------------------------------------------------------
// K2: per-row exact 30th percentile (ranks 1228/1229) + row min.
// Mask is head-independent (scaled = m_dist*r^2, monotone). 8192 blocks x 256.
// ---------------------------------------------------------------------------
__global__ __launch_bounds__(256) void thresh_kernel(
    const float* __restrict__ m_dist,
    float* __restrict__ thr_out, float* __restrict__ min_out)
{
    __shared__ unsigned int hist[1024];
    __shared__ float wred[4];
    __shared__ unsigned int wscan[4];
    __shared__ int b0s, b1s;
    __shared__ unsigned int c0s;
    __shared__ unsigned int ncand;
    __shared__ float cand[256];
    __shared__ float s0s, s1s;

    int t = threadIdx.x;
    size_t rowid = blockIdx.x;
    const float* row = m_dist + rowid * Nc;

    for (int i = t; i < 1024; i += 256) hist[i] = 0u;
    if (t == 0) ncand = 0u;
    __syncthreads();

    float4 vals[4];
    float lmin = 1e30f;
    #pragma unroll
    for (int i = 0; i < 4; i++) {
        float4 v = ((const float4*)row)[t + i * 256];
        vals[i] = v;
        lmin = fminf(lmin, fminf(fminf(v.x, v.y), fminf(v.z, v.w)));
        atomicAdd(&hist[min(1023, (int)(v.x * 1024.0f))], 1u);
        atomicAdd(&hist[min(1023, (int)(v.y * 1024.0f))], 1u);
        atomicAdd(&hist[min(1023, (int)(v.z * 1024.0f))], 1u);
        atomicAdd(&hist[min(1023, (int)(v.w * 1024.0f))], 1u);
    }
    // min reduce
    #pragma unroll
    for (int o = 32; o > 0; o >>= 1) lmin = fminf(lmin, __shfl_xor(lmin, o));
    if ((t & 63) == 0) wred[t >> 6] = lmin;
    __syncthreads();
    float rmin = fminf(fminf(wred[0], wred[1]), fminf(wred[2], wred[3]));

    // scan: thread t owns bins 4t..4t+3
    unsigned int c[4], csum = 0;
    #pragma unroll
    for (int j = 0; j < 4; j++) { c[j] = hist[t * 4 + j]; csum += c[j]; }
    unsigned int inc = csum;
    #pragma unroll
    for (int o = 1; o < 64; o <<= 1) {
        unsigned int nv = __shfl_up(inc, o);
        if ((t & 63) >= o) inc += nv;
    }
    if ((t & 63) == 63) wscan[t >> 6] = inc;
    __syncthreads();
    unsigned int wpref = 0;
    for (int wv = 0; wv < (t >> 6); wv++) wpref += wscan[wv];
    unsigned int P = wpref + inc - csum;    // values in bins < 4t

    const unsigned int R0 = 1228u, R1 = 1229u;   // 0-indexed order stats
    unsigned int cum = P;
    #pragma unroll
    for (int j = 0; j < 4; j++) {
        unsigned int lo = cum, hi = cum + c[j];
        if (R0 >= lo && R0 < hi) { b0s = t * 4 + j; c0s = lo; }
        if (R1 >= lo && R1 < hi) { b1s = t * 4 + j; }
        cum = hi;
    }
    __syncthreads();
    int b0 = b0s, b1 = b1s;
    unsigned int C0 = c0s;

    // gather candidates in bins [b0, b1]
    #pragma unroll
    for (int i = 0; i < 4; i++) {
        float a[4] = {vals[i].x, vals[i].y, vals[i].z, vals[i].w};
        #pragma unroll
        for (int j = 0; j < 4; j++) {
            int bx = min(1023, (int)(a[j] * 1024.0f));
            if (bx >= b0 && bx <= b1) {
                unsigned int p = atomicAdd(&ncand, 1u);
                if (p < 256u) cand[p] = a[j];
            }
        }
    }
    __syncthreads();
    unsigned int nc = min(ncand, 256u);
    if ((unsigned int)t < nc) {
        float v = cand[t];
        unsigned int rk = C0;
        for (unsigned int j = 0; j < nc; j++) {
            float u = cand[j];
            rk += (u < v || (u == v && j < (unsigned int)t)) ? 1u : 0u;
        }
        if (rk == R0) s0s = v;
        if (rk == R1) s1s = v;
    }
    __syncthreads();
    if (t == 0) {
        thr_out[rowid] = 0.5f * (s0s + s1s);  // any value in [s0,s1) gives same mask
        min_out[rowid] = rmin;
    }
}

// ---------------------------------------------------------------------------
// K3: fused mask + softmax-numerator + PV (bf16 MFMA), split-K over j.
// grid = S * B * (N/32) blocks, 512 threads (8 waves: wave = (rowhalf, head)).
// R4 structure + VALU diet:
//  - mask applied ONCE at staging (head-independent): masked d -> 3e38, so the
//    per-head inner is just exp2(fma(d,cc,-mn*cc)) — exp2(-huge)=0 exactly.
//  - packed bf16 convert (__float22bfloat162_rn).
// XOR-swizzled unpadded LDS: ms 8KB + vt 32KB = 40960B -> 4 blocks/CU;
// __launch_bounds__(512,8) caps VGPR at 64 (32 waves/CU). NO register
// prefetch (R3: spilled, WRITE_SIZE 320MB).
// ---------------------------------------------------------------------------
#define NT 32
#define JT 64
#define BIGF 3.0e38f

__global__ __launch_bounds__(512, 8) void attn_kernel(
    const float* __restrict__ m_dist, const float* __restrict__ rr,
    const unsigned short* __restrict__ vt_g,
    const float* __restrict__ thr_g, const float* __restrict__ min_g,
    float* __restrict__ Op, float* __restrict__ Zp, int jlen)
{
    __shared__ float ms[NT * 64];                 // 8 KB, chunk c at c^(row&15)
    __shared__ unsigned short vt[Hc * VDc * 64];  // 32 KB, chunk c at c^(row&7)

    int t = threadIdx.x;
    const int nblk = Bc * (Nc / NT);        // 256
    int js = blockIdx.x / nblk;
    int rb = blockIdx.x - js * nblk;
    int b  = rb >> 7;                       // Nc/NT = 128 row-tiles
    int n0 = (rb & 127) * NT;
    int j0 = js * jlen;

    int lane = t & 63, q = lane >> 4, m16 = lane & 15;
    int w = t >> 6;                         // wave 0..7
    int h = w & 3, rh = w >> 2;
    int row = rh * 16 + m16;                // local A-row this lane owns

    float mn = min_g[b * Nc + n0 + row];
    float rv = rr[h];
    float cc = -(rv * rv) * 1.4426950408889634f;   // -r^2 * log2(e)
    float nmncc = -mn * cc;                        // w = exp2(fma(d, cc, nmncc))

    f4v acc[4];
    #pragma unroll
    for (int ct = 0; ct < 4; ct++) acc[ct] = (f4v){0.f, 0.f, 0.f, 0.f};
    float zacc = 0.f;

    const float* mbase = m_dist + ((size_t)b * Nc + n0) * Nc + j0;
    const unsigned short* vtb = vt_g + ((size_t)b * Hc * VDc) * Nc + j0;

    // staging maps (swizzled LDS destinations)
    int mrow = t >> 4, mch = t & 15;        // ms: 32 rows x 16 float4-chunks
    int msw  = mrow * 64 + ((mch ^ (mrow & 15)) << 2);
    float thm = thr_g[b * Nc + n0 + mrow];  // staging-row threshold (premask)
    int vrow0 = t >> 3, vch = t & 7;        // vt: rows t>>3 + i*64, 8 chunks

    // A-read swizzled chunk offsets for this lane (row&15 == m16)
    int a00 = row * 64 + (((q * 2 + 0) ^ m16) << 2);       // ks=0
    int a01 = row * 64 + (((q * 2 + 1) ^ m16) << 2);
    int a10 = row * 64 + (((8 + q * 2 + 0) ^ m16) << 2);   // ks=1
    int a11 = row * 64 + (((8 + q * 2 + 1) ^ m16) << 2);

    for (int jt = 0; jt < jlen; jt += JT) {
        // stage ms (32 x 64 f32): 1 float4/thread, PREMASKED, swizzled dest
        {
            float4 v = *(const float4*)(mbase + (size_t)mrow * Nc + jt + mch * 4);
            v.x = (v.x <= thm) ? v.x : BIGF;
            v.y = (v.y <= thm) ? v.y : BIGF;
            v.z = (v.z <= thm) ? v.z : BIGF;
            v.w = (v.w <= thm) ? v.w : BIGF;
            *(float4*)&ms[msw] = v;
        }
        // stage vt (256 rows x 64 j bf16): 4 float4/thread, swizzled dest
        #pragma unroll
        for (int i = 0; i < 4; i++) {
            int rrow = vrow0 + i * 64;
            *(float4*)&vt[rrow * 64 + ((vch ^ (rrow & 7)) << 3)] =
                *(const float4*)(vtb + (size_t)rrow * Nc + jt + vch * 8);
        }
        __syncthreads();

        const unsigned short* vb = &vt[(h * VDc) * 64];
        #pragma unroll
        for (int ks = 0; ks < 2; ks++) {
            float4 a0 = *(const float4*)&ms[ks ? a10 : a00];
            float4 a1 = *(const float4*)&ms[ks ? a11 : a01];
            float w0 = __builtin_amdgcn_exp2f(__builtin_fmaf(a0.x, cc, nmncc));
            float w1 = __builtin_amdgcn_exp2f(__builtin_fmaf(a0.y, cc, nmncc));
            float w2 = __builtin_amdgcn_exp2f(__builtin_fmaf(a0.z, cc, nmncc));
            float w3 = __builtin_amdgcn_exp2f(__builtin_fmaf(a0.w, cc, nmncc));
            float w4 = __builtin_amdgcn_exp2f(__builtin_fmaf(a1.x, cc, nmncc));
            float w5 = __builtin_amdgcn_exp2f(__builtin_fmaf(a1.y, cc, nmncc));
            float w6 = __builtin_amdgcn_exp2f(__builtin_fmaf(a1.z, cc, nmncc));
            float w7 = __builtin_amdgcn_exp2f(__builtin_fmaf(a1.w, cc, nmncc));
            zacc += ((w0 + w1) + (w2 + w3)) + ((w4 + w5) + (w6 + w7));
            union { s8v v; __hip_bfloat162 h2[4]; } afu;
            afu.h2[0] = __float22bfloat162_rn((float2){w0, w1});
            afu.h2[1] = __float22bfloat162_rn((float2){w2, w3});
            afu.h2[2] = __float22bfloat162_rn((float2){w4, w5});
            afu.h2[3] = __float22bfloat162_rn((float2){w6, w7});
            #pragma unroll
            for (int ct = 0; ct < 4; ct++) {
                int brow = ct * 16 + m16;
                s8v bf = *(const s8v*)(vb + brow * 64 + (((ks * 4 + q) ^ (m16 & 7)) << 3));
                acc[ct] = __builtin_amdgcn_mfma_f32_16x16x32_bf16(afu.v, bf, acc[ct], 0, 0, 0);
            }
        }
        __syncthreads();
    }

    // Z: lanes sharing m16 across q (xor 16, 32)
    zacc += __shfl_xor(zacc, 16);
    zacc += __shfl_xor(zacc, 32);
    if (q == 0)
        Zp[(((size_t)js * Bc + b) * Hc + h) * Nc + n0 + row] = zacc;

    // partial O: D row = q*4+rg (within the 16), col = ct*16+m16
    #pragma unroll
    for (int ct = 0; ct < 4; ct++) {
        #pragma unroll
        for (int rg = 0; rg < 4; rg++) {
            int nl = rh * 16 + q * 4 + rg;
            Op[(((size_t)js * Bc + b) * Nc + n0 + nl) * HIDc + h * VDc + ct * 16 + m16]
                = acc[ct][rg];
        }
    }
}

// ---------------------------------------------------------------------------
// K4: combine split-K partials, normalize, exact GELU. f32x4 per thread.
// grid = B*N*HID/1024 = 2048 blocks x 256.
// ---------------------------------------------------------------------------
__global__ __launch_bounds__(256) void combine_kernel(
    const float* __restrict__ Op, const float* __restrict__ Zp,
    float* __restrict__ out, int S)
{
    int g = blockIdx.x * 256 + threadIdx.x;       // float4 index
    int c4 = g & 63;
    int n  = (g >> 6) & (Nc - 1);
    int b  = g >> 18;                             // 64 * 4096 = 2^18
    int h  = c4 >> 4;

    float z = 0.f;
    float4 v = {0.f, 0.f, 0.f, 0.f};
    for (int s = 0; s < S; s++) {
        z += Zp[(((size_t)s * Bc + b) * Hc + h) * Nc + n];
        float4 p = *(const float4*)&Op[(((size_t)s * Bc + b) * Nc + n) * HIDc + c4 * 4];
        v.x += p.x; v.y += p.y; v.z += p.z; v.w += p.w;
    }
    float iz = 1.0f / z;
    float4 o;
    float u;
    u = v.x * iz; o.x = 0.5f * u * (1.0f + erff(u * 0.7071067811865476f));
    u = v.y * iz; o.y = 0.5f * u * (1.0f + erff(u * 0.7071067811865476f));
    u = v.z * iz; o.z = 0.5f * u * (1.0f + erff(u * 0.7071067811865476f));
    u = v.w * iz; o.w = 0.5f * u * (1.0f + erff(u * 0.7071067811865476f));
    *(float4*)&out[(((size_t)b * Nc + n) * HIDc) + c4 * 4] = o;
}

// ---------------------------------------------------------------------------
extern "C" void kernel_launch(void* const* d_in, const int* in_sizes, int n_in,
                              void* d_out, int out_size, void* d_ws, size_t ws_size,
                              hipStream_t stream) {
    const float* m_dist = (const float*)d_in[0];
    const float* x      = (const float*)d_in[1];
    const float* r      = (const float*)d_in[2];
    const float* weight = (const float*)d_in[3];
    float* out = (float*)d_out;

    char* ws = (char*)d_ws;
    const size_t MB = 1024 * 1024;
    unsigned short* vt = (unsigned short*)ws;            // 4 MiB bf16 VT
    float* thr = (float*)(ws + 4 * MB);                  // 32 KiB
    float* mn  = (float*)(ws + 4 * MB + 32 * 1024);      // 32 KiB
    float* Zp  = (float*)(ws + 4 * MB + 64 * 1024);      // up to 512 KiB
    float* Op  = (float*)(ws + 5 * MB);                  // S * 8 MiB

    // split factor: prefer 4 (needs 37 MiB ws), else 2, else 1
    int S = 4;
    if (ws_size < 5 * MB + 4 * (size_t)(Bc * Nc * HIDc * 4)) S = 2;
    if (ws_size < 5 * MB + 2 * (size_t)(Bc * Nc * HIDc * 4)) S = 1;
    int jlen = Nc / S;

    value_kernel<<<512, 256, 0, stream>>>(x, weight, vt);
    thresh_kernel<<<Bc * Nc, 256, 0, stream>>>(m_dist, thr, mn);
    attn_kernel<<<S * Bc * (Nc / NT), 512, 0, stream>>>(m_dist, r, vt, thr, mn, Op, Zp, jlen);
    combine_kernel<<<(Bc * Nc * HIDc) / 1024, 256, 0, stream>>>(Op, Zp, out, S);
}